// Round 6
// baseline (83.829 us; speedup 1.0000x reference)
//
#include <hip/hip_runtime.h>

#define G_TOTAL 16384            // 128 x 128 grid
#define NPTS    8192             // context points
#define SPLIT   64               // p-chunks
#define CHUNK   (NPTS / SPLIT)   // 128 p per block
#define KTILES  4                // k tiles of 32
#define KPB     32               // k per block
#define BLOCK   256

// Raw v_exp_f32 — args in [-1100, 0], no fixup needed.
__device__ __forceinline__ float fast_exp2(float x) {
#if __has_builtin(__builtin_amdgcn_exp2f)
    return __builtin_amdgcn_exp2f(x);
#else
    float r; asm("v_exp_f32 %0, %1" : "=v"(r) : "v"(x)); return r;
#endif
}

// ---------------------------------------------------------------------------
// R6: separable-Gaussian rewrite. exp(-0.5 d2) = Ex[j,p] * Ey[k,p], so the
// 134M-exp inner loop (trans-pipe bound ~16cyc/wave64 — the invariant 35us of
// R3/R4/R5) becomes 3 fma/pair with only ~3M exps recomputed at staging.
//   grid: 256 blocks (4 kTiles x 64 p-chunks) x 256 thr, 1 block/CU (113KB LDS)
//   thread-tile: 8j x 2k x 3c = 48 accumulators
//   B_c[p][k] = Ey * {1, y0, y1} folded at staging -> inner loop is pure fma.
// Partials -> ws[s][c][g] (12.6MB), reduced+normalized by phase3.
// ---------------------------------------------------------------------------
__global__ __launch_bounds__(BLOCK) void enc_phase2_kernel(
    const float* __restrict__ X,   // (8192, 2)
    const float* __restrict__ Y,   // (8192, 2)
    float* __restrict__ ws)        // (SPLIT, 3, 16384) partials
{
    __shared__ float  sEx[CHUNK][128];   // 64 KB
    __shared__ float  sB0[CHUNK][KPB];   // 16 KB each
    __shared__ float  sB1[CHUNK][KPB];
    __shared__ float  sB2[CHUNK][KPB];
    __shared__ float2 sPX[CHUNK];        // scaled context coords
    __shared__ float2 sYY[CHUNK];        // raw Y values

    const int t     = threadIdx.x;
    const int kTile = blockIdx.x & (KTILES - 1);
    const int chunk = blockIdx.x >> 2;
    const int kBase = kTile * KPB;
    const int pBase = chunk * CHUNK;

    const float s    = 0.84932184f;      // sqrt(0.5 * log2(e))
    const float step = 4.0f / 127.0f;

    // ---- stage raw chunk (coalesced), pre-scale X by s
    if (t < CHUNK) {
        float2 xv = ((const float2*)X)[pBase + t];
        sPX[t] = make_float2(xv.x * s, xv.y * s);
    } else {
        sYY[t - CHUNK] = ((const float2*)Y)[pBase + (t - CHUNK)];
    }
    __syncthreads();

    // ---- Ex[p][j] = exp2(-(s*gx_j - s*px_p)^2): 16384 entries, 64/thread
    {
        const int j = t & 127;
        const int pHalf = t >> 7;
        const float gxs = (-2.0f + step * (float)j) * s;
#pragma unroll 8
        for (int i = 0; i < 64; ++i) {
            const int p = pHalf + 2 * i;
            float dx = gxs - sPX[p].x;
            sEx[p][j] = fast_exp2(-dx * dx);
        }
    }
    // ---- B_c[p][k] = Ey * {1, y0, y1}: 4096 entries, 16/thread
    {
        const int k = t & (KPB - 1);
        const int p8 = t >> 5;
        const float gys = (2.0f - step * (float)(kBase + k)) * s;
#pragma unroll 4
        for (int i = 0; i < 16; ++i) {
            const int p = p8 + 8 * i;
            float dy = gys - sPX[p].y;
            float ey = fast_exp2(-dy * dy);
            float2 yv = sYY[p];
            sB0[p][k] = ey;
            sB1[p][k] = ey * yv.x;
            sB2[p][k] = ey * yv.y;
        }
    }
    __syncthreads();

    // ---- main loop: 48 fma per thread per p, 5 small LDS reads
    const int jT = t & 15;          // 16 jT x 8 j = 128
    const int kT = t >> 4;          // 16 kT x 2 k = 32
    const int j0 = jT * 8;
    const int k0 = kT * 2;

    float acc[2][3][8];
#pragma unroll
    for (int k = 0; k < 2; ++k)
#pragma unroll
        for (int c = 0; c < 3; ++c)
#pragma unroll
            for (int j = 0; j < 8; ++j) acc[k][c][j] = 0.0f;

#pragma unroll 4
    for (int p = 0; p < CHUNK; ++p) {
        float4 exA = *(const float4*)&sEx[p][j0];      // b128, 32B-aligned
        float4 exB = *(const float4*)&sEx[p][j0 + 4];
        float2 b0  = *(const float2*)&sB0[p][k0];      // b64 broadcasts
        float2 b1  = *(const float2*)&sB1[p][k0];
        float2 b2  = *(const float2*)&sB2[p][k0];
        float ex[8] = {exA.x, exA.y, exA.z, exA.w, exB.x, exB.y, exB.z, exB.w};
        float bk0[2] = {b0.x, b0.y}, bk1[2] = {b1.x, b1.y}, bk2[2] = {b2.x, b2.y};
#pragma unroll
        for (int k = 0; k < 2; ++k)
#pragma unroll
            for (int j = 0; j < 8; ++j) {
                acc[k][0][j] = fmaf(ex[j], bk0[k], acc[k][0][j]);
                acc[k][1][j] = fmaf(ex[j], bk1[k], acc[k][1][j]);
                acc[k][2][j] = fmaf(ex[j], bk2[k], acc[k][2][j]);
            }
    }

    // ---- write partials: ws[chunk][c][g], 2x float4 per (k,c)
#pragma unroll
    for (int k = 0; k < 2; ++k) {
        const int g = (kBase + k0 + k) * 128 + j0;
#pragma unroll
        for (int c = 0; c < 3; ++c) {
            float* w = ws + ((size_t)(chunk * 3 + c)) * G_TOTAL + g;
            *(float4*)&w[0] = make_float4(acc[k][c][0], acc[k][c][1], acc[k][c][2], acc[k][c][3]);
            *(float4*)&w[4] = make_float4(acc[k][c][4], acc[k][c][5], acc[k][c][6], acc[k][c][7]);
        }
    }
}

// ---------------------------------------------------------------------------
// Phase 3: reduce over SPLIT partials + normalize, write final output.
// ---------------------------------------------------------------------------
__global__ __launch_bounds__(256) void reduce_norm_kernel(
    const float* __restrict__ ws, float* __restrict__ out)
{
    const int g = blockIdx.x * 256 + threadIdx.x;
    float c0 = 0.0f, c1 = 0.0f, c2 = 0.0f;
#pragma unroll 8
    for (int sp = 0; sp < SPLIT; ++sp) {
        const float* w = ws + (size_t)(sp * 3) * G_TOTAL;
        c0 += w[g];
        c1 += w[G_TOTAL + g];
        c2 += w[2 * G_TOTAL + g];
    }
    float inv = 1.0f / c0;
    out[g]               = c0;
    out[G_TOTAL + g]     = c1 * inv;
    out[2 * G_TOTAL + g] = c2 * inv;
}

// ---------------------------------------------------------------------------
extern "C" void kernel_launch(void* const* d_in, const int* in_sizes, int n_in,
                              void* d_out, int out_size, void* d_ws, size_t ws_size,
                              hipStream_t stream) {
    const float* X = (const float*)d_in[0];
    const float* Y = (const float*)d_in[1];
    float* out = (float*)d_out;
    float* ws  = (float*)d_ws;    // needs SPLIT*3*16384*4 = 12.6 MB (have 256 MB)

    enc_phase2_kernel<<<KTILES * SPLIT, BLOCK, 0, stream>>>(X, Y, ws);
    reduce_norm_kernel<<<G_TOTAL / 256, 256, 0, stream>>>(ws, out);
}